// Round 1
// baseline (23983.986 us; speedup 1.0000x reference)
//
#include <hip/hip_runtime.h>
#include <hip/hip_bf16.h>

#define BB 16
#define TT 1024
#define FF 128
#define RR 2048
#define HALF 1024

// h0[b][r] = start[r]
__global__ void init_h_kernel(float* __restrict__ h, const float* __restrict__ start) {
    int idx = blockIdx.x * blockDim.x + threadIdx.x;   // 0 .. B*R
    if (idx < BB * RR) {
        int r = idx & (RR - 1);
        h[idx] = start[r];
    }
}

// One recurrence step. Grid: 256 blocks (8 rows of W_rec each) x 512 threads.
// Each half-wave (32 lanes) owns one batch b; lane kl in [0,32) sweeps
// k = kl*4 + j*128 as float4 (fully coalesced 512B segments; W addresses are
// identical across the two half-waves -> broadcast dedup).
__global__ __launch_bounds__(512, 2) void step_kernel(
    const float* __restrict__ inputs,   // [B,T,F]
    const float* __restrict__ Win,      // [R,F]
    const float* __restrict__ Wrec,     // [R,R]
    const float* __restrict__ bias,     // [R]
    const float* __restrict__ h_cur,    // [B,R]
    float* __restrict__ h_next,         // [B,R]
    float* __restrict__ out,            // [B,T,HALF]
    int t)
{
    const int tid  = threadIdx.x;
    const int wave = tid >> 6;            // 0..7
    const int half = (tid >> 5) & 1;      // which half-wave
    const int kl   = tid & 31;            // k-lane within half-wave
    const int b    = wave * 2 + half;     // 0..15
    const int r0   = blockIdx.x * 8;      // row block

    float acc[8];
#pragma unroll
    for (int r = 0; r < 8; ++r) acc[r] = 0.0f;

    // Fused input projection: u[r] = dot(inputs[b,t,:], Win[r,:]) for r < HALF
    if (r0 < HALF) {
        const float4 in4 = *reinterpret_cast<const float4*>(
            inputs + ((size_t)b * TT + t) * FF + kl * 4);
#pragma unroll
        for (int r = 0; r < 8; ++r) {
            const float4 w4 = *reinterpret_cast<const float4*>(
                Win + (size_t)(r0 + r) * FF + kl * 4);
            acc[r] += in4.x * w4.x + in4.y * w4.y + in4.z * w4.z + in4.w * w4.w;
        }
    }

    // Recurrent matmul partials: k = kl*4 + j*128
    const float* hb = h_cur + (size_t)b * RR;
#pragma unroll 2
    for (int j = 0; j < 16; ++j) {
        const int k = kl * 4 + j * 128;
        const float4 h4 = *reinterpret_cast<const float4*>(hb + k);
#pragma unroll
        for (int r = 0; r < 8; ++r) {
            const float4 w4 = *reinterpret_cast<const float4*>(
                Wrec + (size_t)(r0 + r) * RR + k);
            acc[r] = fmaf(h4.x, w4.x, acc[r]);
            acc[r] = fmaf(h4.y, w4.y, acc[r]);
            acc[r] = fmaf(h4.z, w4.z, acc[r]);
            acc[r] = fmaf(h4.w, w4.w, acc[r]);
        }
    }

    // Reduce the 32 k-partials within each half-wave (masks stay inside 32 lanes)
#pragma unroll
    for (int r = 0; r < 8; ++r) {
        float v = acc[r];
        v += __shfl_xor(v, 1);
        v += __shfl_xor(v, 2);
        v += __shfl_xor(v, 4);
        v += __shfl_xor(v, 8);
        v += __shfl_xor(v, 16);
        acc[r] = v;
    }

    __shared__ float red[BB][8];
    if (kl == 0) {
#pragma unroll
        for (int r = 0; r < 8; ++r) red[b][r] = acc[r];
    }
    __syncthreads();

    // Finalize: 128 threads, one per (b, r)
    if (tid < BB * 8) {
        const int rr = tid & 7;
        const int bb = tid >> 3;
        const int r  = r0 + rr;
        const float pre = red[bb][rr] + bias[r];
        const float h_old = h_cur[(size_t)bb * RR + r];
        const float hn = 0.05f * h_old + 0.95f * tanhf(pre);
        h_next[(size_t)bb * RR + r] = hn;
        if (r0 >= HALF) {
            out[((size_t)bb * TT + t) * HALF + (r - HALF)] = hn;
        }
    }
}

extern "C" void kernel_launch(void* const* d_in, const int* in_sizes, int n_in,
                              void* d_out, int out_size, void* d_ws, size_t ws_size,
                              hipStream_t stream) {
    const float* inputs = (const float*)d_in[0];   // [B,T,F]
    const float* Win    = (const float*)d_in[1];   // [R,F]
    const float* Wrec   = (const float*)d_in[2];   // [R,R]
    const float* bias   = (const float*)d_in[3];   // [R]
    const float* start  = (const float*)d_in[4];   // [R]
    float* out = (float*)d_out;                    // [B,T,HALF]

    float* hA = (float*)d_ws;                      // [B,R]
    float* hB = hA + (size_t)BB * RR;              // [B,R]

    init_h_kernel<<<(BB * RR + 255) / 256, 256, 0, stream>>>(hA, start);

    for (int t = 0; t < TT; ++t) {
        const float* hc = (t & 1) ? hB : hA;
        float*       hn = (t & 1) ? hA : hB;
        step_kernel<<<256, 512, 0, stream>>>(inputs, Win, Wrec, bias, hc, hn, out, t);
    }
}